// Round 1
// baseline (420.714 us; speedup 1.0000x reference)
//
#include <hip/hip_runtime.h>
#include <math.h>

#define NB_B 2
#define NB_N 4096
#define NB_DIM 1024
#define NB_H 16
#define NB_D 64
#define NB_CTX 3072

typedef __attribute__((ext_vector_type(8))) short short8;
typedef __attribute__((ext_vector_type(4))) float f32x4;

__device__ __forceinline__ unsigned short f2bf(float f) {
  union { float f; unsigned u; } v; v.f = f;
  unsigned r = v.u + 0x7fffu + ((v.u >> 16) & 1u);
  return (unsigned short)(r >> 16);
}

__device__ __forceinline__ void async16(const void* g, void* l) {
  typedef const unsigned int __attribute__((address_space(1)))* gas_t;
  typedef unsigned int __attribute__((address_space(3)))* las_t;
  __builtin_amdgcn_global_load_lds((gas_t)(unsigned long long)g,
                                   (las_t)(unsigned)(unsigned long long)l,
                                   16, 0, 0);
}

// ---------------- convert x (fp32 -> bf16) ----------------
__global__ void k_conv_x(const float* __restrict__ x, ushort4* __restrict__ xb, int n4) {
  int i = blockIdx.x * blockDim.x + threadIdx.x;
  int stride = gridDim.x * blockDim.x;
  const float4* x4 = (const float4*)x;
  for (; i < n4; i += stride) {
    float4 v = x4[i];
    ushort4 o;
    o.x = f2bf(v.x); o.y = f2bf(v.y); o.z = f2bf(v.z); o.w = f2bf(v.w);
    xb[i] = o;
  }
}

// ---------------- transpose weights (fp32 [K][C] -> bf16 [C][K]) ----------------
__global__ void k_conv_wT(const float* __restrict__ Wq, const float* __restrict__ Wkv,
                          const float* __restrict__ Wo,
                          unsigned short* __restrict__ WqkvT, unsigned short* __restrict__ WoT) {
  __shared__ float tile[64][65];
  const float* W; unsigned short* out;
  int z = blockIdx.z;
  if (z == 0)      { W = Wq;  out = WqkvT; }
  else if (z == 1) { W = Wkv; out = WqkvT + 1024 * 1024; }
  else             { W = Wo;  out = WoT; }
  int c0 = blockIdx.x * 64, k0 = blockIdx.y * 64;
  int tx = threadIdx.x & 63, ty = threadIdx.x >> 6;   // 64 x 4
  #pragma unroll
  for (int i = 0; i < 16; ++i) {
    int k = ty + i * 4;
    tile[k][tx] = W[(long)(k0 + k) * 1024 + c0 + tx];
  }
  __syncthreads();
  #pragma unroll
  for (int i = 0; i < 16; ++i) {
    int c = ty + i * 4;
    out[(long)(c0 + c) * 1024 + k0 + tx] = f2bf(tile[tx][c]);
  }
}

// ---------------- bf16 GEMM: C[M][ldc] = A[M][K] * Bt[N][K]^T (+bias) ----------------
// 128x128 tile, 256 threads (4 waves), 16x16x32 bf16 MFMA, global_load_lds staging
__global__ __launch_bounds__(256) void k_gemm_bt(
    const unsigned short* __restrict__ A,
    const unsigned short* __restrict__ Bt,
    float* __restrict__ C,
    const float* __restrict__ bias,
    int K, int ldc)
{
  __shared__ unsigned short As[128 * 32];
  __shared__ unsigned short Bs[128 * 32];
  const int tid = threadIdx.x;
  const int w = tid >> 6, lane = tid & 63;
  const int wr = w >> 1, wc = w & 1;
  const int quad = lane >> 4, l15 = lane & 15;
  const long tm = (long)blockIdx.y * 128, tn = (long)blockIdx.x * 128;

  f32x4 acc[4][4];
  #pragma unroll
  for (int i = 0; i < 4; ++i)
    #pragma unroll
    for (int j = 0; j < 4; ++j)
      acc[i][j] = (f32x4){0.f, 0.f, 0.f, 0.f};

  const unsigned short* Ag0 = A + (tm + w * 16 + (lane >> 2)) * K + (lane & 3) * 8;
  const unsigned short* Bg0 = Bt + (tn + w * 16 + (lane >> 2)) * K + (lane & 3) * 8;
  const unsigned short* Ag1 = Ag0 + (long)64 * K;
  const unsigned short* Bg1 = Bg0 + (long)64 * K;
  unsigned short* Al0 = &As[(w * 16) * 32];
  unsigned short* Al1 = &As[(64 + w * 16) * 32];
  unsigned short* Bl0 = &Bs[(w * 16) * 32];
  unsigned short* Bl1 = &Bs[(64 + w * 16) * 32];

  for (int k0 = 0; k0 < K; k0 += 32) {
    __syncthreads();
    async16(Ag0 + k0, Al0);
    async16(Ag1 + k0, Al1);
    async16(Bg0 + k0, Bl0);
    async16(Bg1 + k0, Bl1);
    __syncthreads();
    short8 af[4], bfr[4];
    #pragma unroll
    for (int i = 0; i < 4; ++i)
      af[i] = *(const short8*)&As[(wr * 64 + i * 16 + l15) * 32 + quad * 8];
    #pragma unroll
    for (int j = 0; j < 4; ++j)
      bfr[j] = *(const short8*)&Bs[(wc * 64 + j * 16 + l15) * 32 + quad * 8];
    #pragma unroll
    for (int i = 0; i < 4; ++i)
      #pragma unroll
      for (int j = 0; j < 4; ++j)
        acc[i][j] = __builtin_amdgcn_mfma_f32_16x16x32_bf16(af[i], bfr[j], acc[i][j], 0, 0, 0);
  }

  #pragma unroll
  for (int j = 0; j < 4; ++j) {
    const long col = tn + wc * 64 + j * 16 + l15;
    const float bv = bias ? bias[col] : 0.0f;
    #pragma unroll
    for (int i = 0; i < 4; ++i) {
      #pragma unroll
      for (int r = 0; r < 4; ++r) {
        const long row = tm + wr * 64 + i * 16 + quad * 4 + r;
        C[row * ldc + col] = acc[i][j][r] + bv;
      }
    }
  }
}

// ---------------- rope + LN: qkv_raw fp32 -> q_scaled bf16, lkv bf16 ----------------
// one wave per (b,n,h) row; lane = d
__global__ __launch_bounds__(256) void k_rope_ln(
    const float* __restrict__ qkv_raw,
    unsigned short* __restrict__ qf,
    unsigned short* __restrict__ lkv,
    const float* __restrict__ ln_g,
    const float* __restrict__ ln_b)
{
  const int w = threadIdx.x >> 6, lane = threadIdx.x & 63;
  const int row = blockIdx.x * 4 + w;   // [0, 131072)
  const int m = row >> 4;               // b*4096 + n
  const int h = row & 15;
  const int n = m & 4095, b = m >> 12;
  const int d = lane;

  const float* base = qkv_raw + (long)m * 2048 + h * 64 + d;
  float tq = base[0];
  float tk = base[1024];
  float pq = __shfl_xor(tq, 32);
  float pk = __shfl_xor(tk, 32);
  float sgn = (d < 32) ? -1.f : 1.f;
  int fi = d & 31;
  // inv = 10000^(-fi/32) = 2^(-fi * log2(10000)/32)
  float inv = exp2f(-(float)fi * (13.287712379549449f / 32.0f));
  float ang = (float)n * inv;
  float s, c;
  sincosf(ang, &s, &c);
  float qe = tq * c + sgn * pq * s;
  float ke = tk * c + sgn * pk * s;

  const int bh = b * 16 + h;
  const long obase = ((long)bh * NB_N + n) * 64 + d;
  qf[obase] = f2bf(qe * 0.125f);

  // LayerNorm of ke over 64 lanes
  float sum = ke;
  #pragma unroll
  for (int o = 1; o < 64; o <<= 1) sum += __shfl_xor(sum, o);
  float mu = sum * (1.0f / 64.0f);
  float df = ke - mu;
  float vs = df * df;
  #pragma unroll
  for (int o = 1; o < 64; o <<= 1) vs += __shfl_xor(vs, o);
  float var = vs * (1.0f / 64.0f);
  float rr = rsqrtf(var + 1e-5f);
  lkv[obase] = f2bf(df * rr * ln_g[d] + ln_b[d]);
}

// ---------------- unified flash attention ----------------
// blocks 0..255:  latent  (bh = bx>>3, q-tile = (bx&7)*128, keys [0, 3200+q0lat+... ), causal in latent zone)
// blocks 256..1023: context (block-diag 256-key segments, no mask)
#define NEGF -3.0e38f
__global__ __launch_bounds__(256) void k_attn(
    const unsigned short* __restrict__ qf,
    const unsigned short* __restrict__ lkv,
    unsigned short* __restrict__ attn_out)
{
  __shared__ unsigned short Ks[64 * 72];    // [key][d] padded
  __shared__ unsigned short Vt[64 * 72];    // [d][key] padded
  __shared__ unsigned short QPs[128 * 72];  // Q staging, then per-wave P regions

  const int tid = threadIdx.x;
  const int w = tid >> 6, lane = tid & 63;
  const int quad = lane >> 4, l15 = lane & 15;

  const int bx = blockIdx.x;
  int bh, q0tok, kstart, nkt, q0lat;
  bool latent;
  if (bx < 256) {
    latent = true;
    bh = bx >> 3;
    q0lat = (bx & 7) * 128;
    q0tok = NB_CTX + q0lat;
    kstart = 0;
    nkt = (NB_CTX + q0lat + 128) / 64;  // skip fully-masked key tiles
  } else {
    latent = false;
    int idx = bx - 256;
    bh = idx / 24;
    int r2 = idx % 24;
    int seg = r2 >> 1;
    q0lat = 0;
    q0tok = seg * 256 + (r2 & 1) * 128;
    kstart = seg * 256;
    nkt = 4;
  }

  const unsigned short* qbase = qf + ((long)bh * NB_N + q0tok) * 64;
  const unsigned short* kbase = lkv + (long)bh * NB_N * 64;

  // stage Q tile (128 x 64) into QPs
  #pragma unroll
  for (int p = 0; p < 4; ++p) {
    int ci = p * 256 + tid;          // 0..1023
    int row = ci >> 3, dc = ci & 7;
    uint4 v = *(const uint4*)(qbase + row * 64 + dc * 8);
    *(uint4*)&QPs[row * 72 + dc * 8] = v;
  }
  __syncthreads();

  short8 qfr[2][2];
  #pragma unroll
  for (int i = 0; i < 2; ++i)
    #pragma unroll
    for (int kc = 0; kc < 2; ++kc)
      qfr[i][kc] = *(const short8*)&QPs[(w * 32 + i * 16 + l15) * 72 + kc * 32 + quad * 8];

  f32x4 O[2][4];
  float mi[2][4], li[2][4];
  #pragma unroll
  for (int i = 0; i < 2; ++i) {
    #pragma unroll
    for (int j = 0; j < 4; ++j) O[i][j] = (f32x4){0.f, 0.f, 0.f, 0.f};
    #pragma unroll
    for (int r = 0; r < 4; ++r) { mi[i][r] = NEGF; li[i][r] = 0.f; }
  }

  for (int kt = 0; kt < nkt; ++kt) {
    const int key0 = kstart + kt * 64;
    __syncthreads();
    // stage K tile; also transpose into Vt
    #pragma unroll
    for (int p = 0; p < 2; ++p) {
      int ci = p * 256 + tid;        // 0..511
      int key = ci >> 3, dc = ci & 7;
      uint4 v = *(const uint4*)(kbase + (long)(key0 + key) * 64 + dc * 8);
      *(uint4*)&Ks[key * 72 + dc * 8] = v;
      const unsigned short* ev = (const unsigned short*)&v;
      #pragma unroll
      for (int j = 0; j < 8; ++j)
        Vt[(dc * 8 + j) * 72 + key] = ev[j];
    }
    __syncthreads();

    // S = Q K^T  (per wave: 32 q-rows x 64 keys)
    f32x4 sv[2][4];
    #pragma unroll
    for (int i = 0; i < 2; ++i)
      #pragma unroll
      for (int j = 0; j < 4; ++j)
        sv[i][j] = (f32x4){0.f, 0.f, 0.f, 0.f};
    #pragma unroll
    for (int kc = 0; kc < 2; ++kc) {
      short8 kf[4];
      #pragma unroll
      for (int j = 0; j < 4; ++j)
        kf[j] = *(const short8*)&Ks[(j * 16 + l15) * 72 + kc * 32 + quad * 8];
      #pragma unroll
      for (int i = 0; i < 2; ++i)
        #pragma unroll
        for (int j = 0; j < 4; ++j)
          sv[i][j] = __builtin_amdgcn_mfma_f32_16x16x32_bf16(qfr[i][kc], kf[j], sv[i][j], 0, 0, 0);
    }

    // causal mask among latents
    if (latent && key0 + 63 >= NB_CTX) {
      #pragma unroll
      for (int j = 0; j < 4; ++j) {
        int gk = key0 + j * 16 + l15;
        if (gk >= NB_CTX) {
          int kl = gk - NB_CTX;
          #pragma unroll
          for (int i = 0; i < 2; ++i)
            #pragma unroll
            for (int r = 0; r < 4; ++r) {
              int qrow = q0lat + w * 32 + i * 16 + quad * 4 + r;
              if (kl > qrow) sv[i][j][r] = NEGF;
            }
        }
      }
    }

    // online softmax (rows live in 16-lane quads)
    #pragma unroll
    for (int i = 0; i < 2; ++i) {
      #pragma unroll
      for (int r = 0; r < 4; ++r) {
        float mx = fmaxf(fmaxf(sv[i][0][r], sv[i][1][r]), fmaxf(sv[i][2][r], sv[i][3][r]));
        #pragma unroll
        for (int o = 1; o < 16; o <<= 1) mx = fmaxf(mx, __shfl_xor(mx, o));
        float mnew = fmaxf(mi[i][r], mx);
        float alpha = __expf(mi[i][r] - mnew);
        mi[i][r] = mnew;
        float rs = 0.f;
        #pragma unroll
        for (int j = 0; j < 4; ++j) {
          float p = __expf(sv[i][j][r] - mnew);
          sv[i][j][r] = p;
          rs += p;
        }
        #pragma unroll
        for (int o = 1; o < 16; o <<= 1) rs += __shfl_xor(rs, o);
        li[i][r] = li[i][r] * alpha + rs;
        #pragma unroll
        for (int jd = 0; jd < 4; ++jd) O[i][jd][r] *= alpha;
      }
    }

    // P (C-layout) -> LDS (per-wave region) -> A-layout frags
    const int pbase = w * 2304;   // 32 rows * 72
    #pragma unroll
    for (int i = 0; i < 2; ++i)
      #pragma unroll
      for (int j = 0; j < 4; ++j)
        #pragma unroll
        for (int r = 0; r < 4; ++r)
          QPs[pbase + (i * 16 + quad * 4 + r) * 72 + j * 16 + l15] = f2bf(sv[i][j][r]);

    // O += P V
    #pragma unroll
    for (int kc = 0; kc < 2; ++kc) {
      short8 pf[2], vf[4];
      #pragma unroll
      for (int i = 0; i < 2; ++i)
        pf[i] = *(const short8*)&QPs[pbase + (i * 16 + l15) * 72 + kc * 32 + quad * 8];
      #pragma unroll
      for (int jd = 0; jd < 4; ++jd)
        vf[jd] = *(const short8*)&Vt[(jd * 16 + l15) * 72 + kc * 32 + quad * 8];
      #pragma unroll
      for (int i = 0; i < 2; ++i)
        #pragma unroll
        for (int jd = 0; jd < 4; ++jd)
          O[i][jd] = __builtin_amdgcn_mfma_f32_16x16x32_bf16(pf[i], vf[jd], O[i][jd], 0, 0, 0);
    }
  }

  // epilogue: O / l -> attn_out [B][N][DIM] bf16 (merged heads)
  const int b = bh >> 4, h = bh & 15;
  #pragma unroll
  for (int i = 0; i < 2; ++i) {
    #pragma unroll
    for (int r = 0; r < 4; ++r) {
      const float inv_l = 1.0f / li[i][r];
      const long tok = q0tok + w * 32 + i * 16 + quad * 4 + r;
      unsigned short* orow = attn_out + ((long)b * NB_N + tok) * NB_DIM + h * 64;
      #pragma unroll
      for (int jd = 0; jd < 4; ++jd)
        orow[jd * 16 + l15] = f2bf(O[i][jd][r] * inv_l);
    }
  }
}

extern "C" void kernel_launch(void* const* d_in, const int* in_sizes, int n_in,
                              void* d_out, int out_size, void* d_ws, size_t ws_size,
                              hipStream_t stream)
{
  const float* x    = (const float*)d_in[0];
  const float* Wq   = (const float*)d_in[1];
  const float* Wkv  = (const float*)d_in[2];
  const float* Wo   = (const float*)d_in[3];
  const float* bo   = (const float*)d_in[4];
  const float* ln_g = (const float*)d_in[5];
  const float* ln_b = (const float*)d_in[6];
  float* out = (float*)d_out;

  char* ws = (char*)d_ws;
  unsigned short* xb     = (unsigned short*)(ws);                      // 16 MB
  unsigned short* WqkvT  = (unsigned short*)(ws + (size_t)(16 << 20)); // 4 MB
  unsigned short* WoT    = (unsigned short*)(ws + (size_t)(20 << 20)); // 2 MB
  float*          qkvraw = (float*)         (ws + (size_t)(22 << 20)); // 64 MB
  unsigned short* qfb    = (unsigned short*)(ws + (size_t)(86 << 20)); // 16 MB
  unsigned short* lkv    = (unsigned short*)(ws + (size_t)(102 << 20));// 16 MB
  unsigned short* aout   = (unsigned short*)(ws + (size_t)(118 << 20));// 16 MB

  hipLaunchKernelGGL(k_conv_x, dim3(2048), dim3(256), 0, stream,
                     x, (ushort4*)xb, (NB_B * NB_N * NB_DIM) / 4);
  hipLaunchKernelGGL(k_conv_wT, dim3(16, 16, 3), dim3(256), 0, stream,
                     Wq, Wkv, Wo, WqkvT, WoT);
  hipLaunchKernelGGL(k_gemm_bt, dim3(16, 64), dim3(256), 0, stream,
                     xb, WqkvT, qkvraw, (const float*)nullptr, 1024, 2048);
  hipLaunchKernelGGL(k_rope_ln, dim3(32768), dim3(256), 0, stream,
                     qkvraw, qfb, lkv, ln_g, ln_b);
  hipLaunchKernelGGL(k_attn, dim3(1024), dim3(256), 0, stream,
                     qfb, lkv, aout);
  hipLaunchKernelGGL(k_gemm_bt, dim3(8, 64), dim3(256), 0, stream,
                     aout, WoT, out, bo, 1024, 1024);
}

// Round 2
// 376.901 us; speedup vs baseline: 1.1162x; 1.1162x over previous
//
#include <hip/hip_runtime.h>
#include <math.h>

#define NB_B 2
#define NB_N 4096
#define NB_DIM 1024
#define NB_H 16
#define NB_D 64
#define NB_CTX 3072

typedef __attribute__((ext_vector_type(8))) short short8;
typedef __attribute__((ext_vector_type(4))) float f32x4;

__device__ __forceinline__ unsigned short f2bf(float f) {
  union { float f; unsigned u; } v; v.f = f;
  unsigned r = v.u + 0x7fffu + ((v.u >> 16) & 1u);
  return (unsigned short)(r >> 16);
}

__device__ __forceinline__ void async16(const void* g, void* l) {
  typedef const unsigned int __attribute__((address_space(1)))* gas_t;
  typedef unsigned int __attribute__((address_space(3)))* las_t;
  __builtin_amdgcn_global_load_lds((gas_t)(unsigned long long)g,
                                   (las_t)(unsigned)(unsigned long long)l,
                                   16, 0, 0);
}

// ---------------- convert x (fp32 -> bf16) ----------------
__global__ void k_conv_x(const float* __restrict__ x, ushort4* __restrict__ xb, int n4) {
  int i = blockIdx.x * blockDim.x + threadIdx.x;
  int stride = gridDim.x * blockDim.x;
  const float4* x4 = (const float4*)x;
  for (; i < n4; i += stride) {
    float4 v = x4[i];
    ushort4 o;
    o.x = f2bf(v.x); o.y = f2bf(v.y); o.z = f2bf(v.z); o.w = f2bf(v.w);
    xb[i] = o;
  }
}

// ---------------- transpose weights (fp32 [K][C] -> bf16 [C][K]) ----------------
__global__ void k_conv_wT(const float* __restrict__ Wq, const float* __restrict__ Wkv,
                          const float* __restrict__ Wo,
                          unsigned short* __restrict__ WqkvT, unsigned short* __restrict__ WoT) {
  __shared__ float tile[64][65];
  const float* W; unsigned short* out;
  int z = blockIdx.z;
  if (z == 0)      { W = Wq;  out = WqkvT; }
  else if (z == 1) { W = Wkv; out = WqkvT + 1024 * 1024; }
  else             { W = Wo;  out = WoT; }
  int c0 = blockIdx.x * 64, k0 = blockIdx.y * 64;
  int tx = threadIdx.x & 63, ty = threadIdx.x >> 6;   // 64 x 4
  #pragma unroll
  for (int i = 0; i < 16; ++i) {
    int k = ty + i * 4;
    tile[k][tx] = W[(long)(k0 + k) * 1024 + c0 + tx];
  }
  __syncthreads();
  #pragma unroll
  for (int i = 0; i < 16; ++i) {
    int c = ty + i * 4;
    out[(long)(c0 + c) * 1024 + k0 + tx] = f2bf(tile[tx][c]);
  }
}

// ---------------- bf16 GEMM: C[M][ldc] = A[M][K] * Bt[N][K]^T (+bias) ----------------
__global__ __launch_bounds__(256) void k_gemm_bt(
    const unsigned short* __restrict__ A,
    const unsigned short* __restrict__ Bt,
    float* __restrict__ C,
    const float* __restrict__ bias,
    int K, int ldc)
{
  __shared__ unsigned short As[128 * 32];
  __shared__ unsigned short Bs[128 * 32];
  const int tid = threadIdx.x;
  const int w = tid >> 6, lane = tid & 63;
  const int wr = w >> 1, wc = w & 1;
  const int quad = lane >> 4, l15 = lane & 15;
  const long tm = (long)blockIdx.y * 128, tn = (long)blockIdx.x * 128;

  f32x4 acc[4][4];
  #pragma unroll
  for (int i = 0; i < 4; ++i)
    #pragma unroll
    for (int j = 0; j < 4; ++j)
      acc[i][j] = (f32x4){0.f, 0.f, 0.f, 0.f};

  const unsigned short* Ag0 = A + (tm + w * 16 + (lane >> 2)) * K + (lane & 3) * 8;
  const unsigned short* Bg0 = Bt + (tn + w * 16 + (lane >> 2)) * K + (lane & 3) * 8;
  const unsigned short* Ag1 = Ag0 + (long)64 * K;
  const unsigned short* Bg1 = Bg0 + (long)64 * K;
  unsigned short* Al0 = &As[(w * 16) * 32];
  unsigned short* Al1 = &As[(64 + w * 16) * 32];
  unsigned short* Bl0 = &Bs[(w * 16) * 32];
  unsigned short* Bl1 = &Bs[(64 + w * 16) * 32];

  for (int k0 = 0; k0 < K; k0 += 32) {
    __syncthreads();
    async16(Ag0 + k0, Al0);
    async16(Ag1 + k0, Al1);
    async16(Bg0 + k0, Bl0);
    async16(Bg1 + k0, Bl1);
    __syncthreads();
    short8 af[4], bfr[4];
    #pragma unroll
    for (int i = 0; i < 4; ++i)
      af[i] = *(const short8*)&As[(wr * 64 + i * 16 + l15) * 32 + quad * 8];
    #pragma unroll
    for (int j = 0; j < 4; ++j)
      bfr[j] = *(const short8*)&Bs[(wc * 64 + j * 16 + l15) * 32 + quad * 8];
    #pragma unroll
    for (int i = 0; i < 4; ++i)
      #pragma unroll
      for (int j = 0; j < 4; ++j)
        acc[i][j] = __builtin_amdgcn_mfma_f32_16x16x32_bf16(af[i], bfr[j], acc[i][j], 0, 0, 0);
  }

  #pragma unroll
  for (int j = 0; j < 4; ++j) {
    const long col = tn + wc * 64 + j * 16 + l15;
    const float bv = bias ? bias[col] : 0.0f;
    #pragma unroll
    for (int i = 0; i < 4; ++i) {
      #pragma unroll
      for (int r = 0; r < 4; ++r) {
        const long row = tm + wr * 64 + i * 16 + quad * 4 + r;
        C[row * ldc + col] = acc[i][j][r] + bv;
      }
    }
  }
}

// ---------------- rope + LN ----------------
__global__ __launch_bounds__(256) void k_rope_ln(
    const float* __restrict__ qkv_raw,
    unsigned short* __restrict__ qf,
    unsigned short* __restrict__ lkv,
    const float* __restrict__ ln_g,
    const float* __restrict__ ln_b)
{
  const int w = threadIdx.x >> 6, lane = threadIdx.x & 63;
  const int row = blockIdx.x * 4 + w;   // [0, 131072)
  const int m = row >> 4;               // b*4096 + n
  const int h = row & 15;
  const int n = m & 4095, b = m >> 12;
  const int d = lane;

  const float* base = qkv_raw + (long)m * 2048 + h * 64 + d;
  float tq = base[0];
  float tk = base[1024];
  float pq = __shfl_xor(tq, 32);
  float pk = __shfl_xor(tk, 32);
  float sgn = (d < 32) ? -1.f : 1.f;
  int fi = d & 31;
  float inv = exp2f(-(float)fi * (13.287712379549449f / 32.0f));
  float ang = (float)n * inv;
  float s, c;
  sincosf(ang, &s, &c);
  float qe = tq * c + sgn * pq * s;
  float ke = tk * c + sgn * pk * s;

  const int bh = b * 16 + h;
  const long obase = ((long)bh * NB_N + n) * 64 + d;
  qf[obase] = f2bf(qe * 0.125f);

  float sum = ke;
  #pragma unroll
  for (int o = 1; o < 64; o <<= 1) sum += __shfl_xor(sum, o);
  float mu = sum * (1.0f / 64.0f);
  float df = ke - mu;
  float vs = df * df;
  #pragma unroll
  for (int o = 1; o < 64; o <<= 1) vs += __shfl_xor(vs, o);
  float var = vs * (1.0f / 64.0f);
  float rr = rsqrtf(var + 1e-5f);
  lkv[obase] = f2bf(df * rr * ln_g[d] + ln_b[d]);
}

// ---------------- unified flash attention (latent split-K + ctx) ----------------
// blocks 0..1023:    latent: s = bx&3, qb = bx>>2 (bh*8+qt). Writes partials.
// blocks 1024..1791: context block-diag, writes aout directly.
#define NEGF -3.0e38f
__global__ __launch_bounds__(256) void k_attn(
    const unsigned short* __restrict__ qf,
    const unsigned short* __restrict__ lkv,
    unsigned short* __restrict__ attn_out,
    float* __restrict__ Opart,
    float* __restrict__ mpart,
    float* __restrict__ lpart)
{
  __shared__ unsigned short Ks[64 * 72];    // [key][d] padded
  __shared__ unsigned short Vt[64 * 72];    // [d][key^((d&56))] swizzled
  __shared__ unsigned short QPs[128 * 72];  // Q staging, then per-wave P regions

  const int tid = threadIdx.x;
  const int w = tid >> 6, lane = tid & 63;
  const int quad = lane >> 4, l15 = lane & 15;

  const int bx = blockIdx.x;
  int bh, q0tok, kstart, kt0, kt1, q0lat, s4 = 0, qb = 0;
  bool latent;
  if (bx < 1024) {
    latent = true;
    s4 = bx & 3;
    qb = bx >> 2;            // bh*8 + qt
    bh = qb >> 3;
    q0lat = (qb & 7) * 128;
    q0tok = NB_CTX + q0lat;
    kstart = 0;
    int nkt = (NB_CTX + q0lat + 128) >> 6;   // skip fully-masked tail tiles
    kt0 = (s4 * nkt) >> 2;
    kt1 = ((s4 + 1) * nkt) >> 2;
  } else {
    latent = false;
    int idx = bx - 1024;
    bh = idx / 24;
    int r2 = idx % 24;
    int seg = r2 >> 1;
    q0lat = 0;
    q0tok = seg * 256 + (r2 & 1) * 128;
    kstart = seg * 256;
    kt0 = 0; kt1 = 4;
  }

  const unsigned short* qbase = qf + ((long)bh * NB_N + q0tok) * 64;
  const unsigned short* kbase = lkv + (long)bh * NB_N * 64;

  // stage Q tile (128 x 64)
  #pragma unroll
  for (int p = 0; p < 4; ++p) {
    int ci = p * 256 + tid;
    int row = ci >> 3, dc = ci & 7;
    uint4 v = *(const uint4*)(qbase + row * 64 + dc * 8);
    *(uint4*)&QPs[row * 72 + dc * 8] = v;
  }
  __syncthreads();

  short8 qfr[2][2];
  #pragma unroll
  for (int i = 0; i < 2; ++i)
    #pragma unroll
    for (int kc = 0; kc < 2; ++kc)
      qfr[i][kc] = *(const short8*)&QPs[(w * 32 + i * 16 + l15) * 72 + kc * 32 + quad * 8];

  f32x4 O[2][4];
  float mi[2][4], li[2][4];
  #pragma unroll
  for (int i = 0; i < 2; ++i) {
    #pragma unroll
    for (int j = 0; j < 4; ++j) O[i][j] = (f32x4){0.f, 0.f, 0.f, 0.f};
    #pragma unroll
    for (int r = 0; r < 4; ++r) { mi[i][r] = NEGF; li[i][r] = 0.f; }
  }

  for (int kt = kt0; kt < kt1; ++kt) {
    const int key0 = kstart + kt * 64;
    __syncthreads();
    // stage K tile; also write V^T with XOR swizzle (kills 8-way bank conflicts)
    #pragma unroll
    for (int p = 0; p < 2; ++p) {
      int ci = p * 256 + tid;
      int key = ci >> 3, dc = ci & 7;
      uint4 v = *(const uint4*)(kbase + (long)(key0 + key) * 64 + dc * 8);
      *(uint4*)&Ks[key * 72 + dc * 8] = v;
      const unsigned short* ev = (const unsigned short*)&v;
      const int sw = key ^ (dc * 8);   // (dc*8) == (d & 56) for d = dc*8+j
      #pragma unroll
      for (int j = 0; j < 8; ++j)
        Vt[(dc * 8 + j) * 72 + sw] = ev[j];
    }
    __syncthreads();

    // S = Q K^T
    f32x4 sv[2][4];
    #pragma unroll
    for (int i = 0; i < 2; ++i)
      #pragma unroll
      for (int j = 0; j < 4; ++j)
        sv[i][j] = (f32x4){0.f, 0.f, 0.f, 0.f};
    #pragma unroll
    for (int kc = 0; kc < 2; ++kc) {
      short8 kf[4];
      #pragma unroll
      for (int j = 0; j < 4; ++j)
        kf[j] = *(const short8*)&Ks[(j * 16 + l15) * 72 + kc * 32 + quad * 8];
      #pragma unroll
      for (int i = 0; i < 2; ++i)
        #pragma unroll
        for (int j = 0; j < 4; ++j)
          sv[i][j] = __builtin_amdgcn_mfma_f32_16x16x32_bf16(qfr[i][kc], kf[j], sv[i][j], 0, 0, 0);
    }

    // causal mask among latents
    if (latent && key0 + 63 >= NB_CTX) {
      #pragma unroll
      for (int j = 0; j < 4; ++j) {
        int gk = key0 + j * 16 + l15;
        if (gk >= NB_CTX) {
          int kl = gk - NB_CTX;
          #pragma unroll
          for (int i = 0; i < 2; ++i)
            #pragma unroll
            for (int r = 0; r < 4; ++r) {
              int qrow = q0lat + w * 32 + i * 16 + quad * 4 + r;
              if (kl > qrow) sv[i][j][r] = NEGF;
            }
        }
      }
    }

    // online softmax
    #pragma unroll
    for (int i = 0; i < 2; ++i) {
      #pragma unroll
      for (int r = 0; r < 4; ++r) {
        float mx = fmaxf(fmaxf(sv[i][0][r], sv[i][1][r]), fmaxf(sv[i][2][r], sv[i][3][r]));
        #pragma unroll
        for (int o = 1; o < 16; o <<= 1) mx = fmaxf(mx, __shfl_xor(mx, o));
        float mnew = fmaxf(mi[i][r], mx);
        float alpha = __expf(mi[i][r] - mnew);
        mi[i][r] = mnew;
        float rs = 0.f;
        #pragma unroll
        for (int j = 0; j < 4; ++j) {
          float p = __expf(sv[i][j][r] - mnew);
          sv[i][j][r] = p;
          rs += p;
        }
        #pragma unroll
        for (int o = 1; o < 16; o <<= 1) rs += __shfl_xor(rs, o);
        li[i][r] = li[i][r] * alpha + rs;
        #pragma unroll
        for (int jd = 0; jd < 4; ++jd) O[i][jd][r] *= alpha;
      }
    }

    // P (C-layout) -> LDS -> A-layout frags
    const int pbase = w * 2304;
    #pragma unroll
    for (int i = 0; i < 2; ++i)
      #pragma unroll
      for (int j = 0; j < 4; ++j)
        #pragma unroll
        for (int r = 0; r < 4; ++r)
          QPs[pbase + (i * 16 + quad * 4 + r) * 72 + j * 16 + l15] = f2bf(sv[i][j][r]);

    // O += P V
    #pragma unroll
    for (int kc = 0; kc < 2; ++kc) {
      short8 pf[2], vf[4];
      #pragma unroll
      for (int i = 0; i < 2; ++i)
        pf[i] = *(const short8*)&QPs[pbase + (i * 16 + l15) * 72 + kc * 32 + quad * 8];
      #pragma unroll
      for (int jd = 0; jd < 4; ++jd) {
        const int row = jd * 16 + l15;
        vf[jd] = *(const short8*)&Vt[row * 72 + ((kc * 32 + quad * 8) ^ (row & 56))];
      }
      #pragma unroll
      for (int i = 0; i < 2; ++i)
        #pragma unroll
        for (int jd = 0; jd < 4; ++jd)
          O[i][jd] = __builtin_amdgcn_mfma_f32_16x16x32_bf16(pf[i], vf[jd], O[i][jd], 0, 0, 0);
    }
  }

  if (latent) {
    // write raw partials (O, m, l); combine kernel normalizes
    const long pb = (long)(s4 * 256 + qb) * 128;
    #pragma unroll
    for (int i = 0; i < 2; ++i) {
      #pragma unroll
      for (int r = 0; r < 4; ++r) {
        const int row = w * 32 + i * 16 + quad * 4 + r;
        if (l15 == 0) { mpart[pb + row] = mi[i][r]; lpart[pb + row] = li[i][r]; }
        float* orow = Opart + (pb + row) * 64;
        #pragma unroll
        for (int jd = 0; jd < 4; ++jd)
          orow[jd * 16 + l15] = O[i][jd][r];
      }
    }
  } else {
    const int b = bh >> 4, h = bh & 15;
    #pragma unroll
    for (int i = 0; i < 2; ++i) {
      #pragma unroll
      for (int r = 0; r < 4; ++r) {
        const float inv_l = 1.0f / li[i][r];
        const long tok = q0tok + w * 32 + i * 16 + quad * 4 + r;
        unsigned short* orow = attn_out + ((long)b * NB_N + tok) * NB_DIM + h * 64;
        #pragma unroll
        for (int jd = 0; jd < 4; ++jd)
          orow[jd * 16 + l15] = f2bf(O[i][jd][r] * inv_l);
      }
    }
  }
}

// ---------------- combine latent split-K partials ----------------
__global__ __launch_bounds__(256) void k_combine(
    const float* __restrict__ Opart, const float* __restrict__ mpart,
    const float* __restrict__ lpart, unsigned short* __restrict__ attn_out)
{
  const int qb = blockIdx.x;        // bh*8 + qt
  const int bh = qb >> 3, qt = qb & 7;
  const int b = bh >> 4, h = bh & 15;
  const int row = threadIdx.x >> 1;
  const int dh = (threadIdx.x & 1) * 32;
  float m[4], l[4];
  float mstar = NEGF;
  #pragma unroll
  for (int s = 0; s < 4; ++s) {
    m[s] = mpart[(s * 256 + qb) * 128 + row];
    l[s] = lpart[(s * 256 + qb) * 128 + row];
    mstar = fmaxf(mstar, m[s]);
  }
  float w[4]; float lsum = 0.f;
  #pragma unroll
  for (int s = 0; s < 4; ++s) { w[s] = __expf(m[s] - mstar); lsum += w[s] * l[s]; }
  const float inv = 1.0f / lsum;
  float o[32];
  #pragma unroll
  for (int e = 0; e < 32; ++e) o[e] = 0.f;
  #pragma unroll
  for (int s = 0; s < 4; ++s) {
    const float4* Op = (const float4*)(Opart + (((long)(s * 256 + qb) * 128 + row) * 64 + dh));
    #pragma unroll
    for (int v = 0; v < 8; ++v) {
      float4 t = Op[v];
      o[v * 4 + 0] += w[s] * t.x; o[v * 4 + 1] += w[s] * t.y;
      o[v * 4 + 2] += w[s] * t.z; o[v * 4 + 3] += w[s] * t.w;
    }
  }
  const long tok = NB_CTX + qt * 128 + row;
  unsigned short* orow = attn_out + ((long)b * NB_N + tok) * NB_DIM + h * 64 + dh;
  #pragma unroll
  for (int e = 0; e < 32; e += 4) {
    ushort4 u;
    u.x = f2bf(o[e] * inv);     u.y = f2bf(o[e + 1] * inv);
    u.z = f2bf(o[e + 2] * inv); u.w = f2bf(o[e + 3] * inv);
    *(ushort4*)(orow + e) = u;
  }
}

extern "C" void kernel_launch(void* const* d_in, const int* in_sizes, int n_in,
                              void* d_out, int out_size, void* d_ws, size_t ws_size,
                              hipStream_t stream)
{
  const float* x    = (const float*)d_in[0];
  const float* Wq   = (const float*)d_in[1];
  const float* Wkv  = (const float*)d_in[2];
  const float* Wo   = (const float*)d_in[3];
  const float* bo   = (const float*)d_in[4];
  const float* ln_g = (const float*)d_in[5];
  const float* ln_b = (const float*)d_in[6];
  float* out = (float*)d_out;

  char* ws = (char*)d_ws;
  unsigned short* xb     = (unsigned short*)(ws);                      // 16 MB
  unsigned short* WqkvT  = (unsigned short*)(ws + (size_t)(16 << 20)); // 4 MB
  unsigned short* WoT    = (unsigned short*)(ws + (size_t)(20 << 20)); // 2 MB
  float*          qkvraw = (float*)         (ws + (size_t)(22 << 20)); // 64 MB (dead after rope_ln)
  unsigned short* qfb    = (unsigned short*)(ws + (size_t)(86 << 20)); // 16 MB
  unsigned short* lkv    = (unsigned short*)(ws + (size_t)(102 << 20));// 16 MB
  unsigned short* aout   = (unsigned short*)(ws + (size_t)(118 << 20));// 16 MB
  // attention split-K partials overlay the dead qkvraw region:
  float* Opart = (float*)(ws + (size_t)(22 << 20));                    // 33.5 MB
  float* mpart = (float*)(ws + (size_t)(56 << 20));                    // 0.5 MB
  float* lpart = (float*)(ws + (size_t)(57 << 20));                    // 0.5 MB

  hipLaunchKernelGGL(k_conv_x, dim3(2048), dim3(256), 0, stream,
                     x, (ushort4*)xb, (NB_B * NB_N * NB_DIM) / 4);
  hipLaunchKernelGGL(k_conv_wT, dim3(16, 16, 3), dim3(256), 0, stream,
                     Wq, Wkv, Wo, WqkvT, WoT);
  hipLaunchKernelGGL(k_gemm_bt, dim3(16, 64), dim3(256), 0, stream,
                     xb, WqkvT, qkvraw, (const float*)nullptr, 1024, 2048);
  hipLaunchKernelGGL(k_rope_ln, dim3(32768), dim3(256), 0, stream,
                     qkvraw, qfb, lkv, ln_g, ln_b);
  hipLaunchKernelGGL(k_attn, dim3(1792), dim3(256), 0, stream,
                     qfb, lkv, aout, Opart, mpart, lpart);
  hipLaunchKernelGGL(k_combine, dim3(256), dim3(256), 0, stream,
                     Opart, mpart, lpart, aout);
  hipLaunchKernelGGL(k_gemm_bt, dim3(8, 64), dim3(256), 0, stream,
                     aout, WoT, out, bo, 1024, 1024);
}